// Round 9
// baseline (598.990 us; speedup 1.0000x reference)
//
#include <hip/hip_runtime.h>

#define B_   8
#define K_   256
#define C_   8
#define PS   64
#define H_   512
#define W_   512
#define TH   32
#define TW   32
#define LPAD 33   // padded LDS row stride (floats) -> spread banks across rows

// Detect whether coords buffer is int64 (little-endian lo/hi pairs, hi==0 since
// coords are small non-negative) or already int32; write decoded int32 coords.
__global__ void decode_coords_kernel(const int* __restrict__ raw,
                                     int* __restrict__ coords, int n) {
    __shared__ int s_nonzero;
    if (threadIdx.x == 0) s_nonzero = 0;
    __syncthreads();
    int local = 0;
    for (int i = 2 * threadIdx.x + 1; i < n; i += 2 * blockDim.x) {
        if (raw[i] != 0) local = 1;
    }
    if (local) atomicOr(&s_nonzero, 1);
    __syncthreads();
    bool is64 = (s_nonzero == 0);  // all odd words zero -> int64 layout
    for (int i = threadIdx.x; i < n; i += blockDim.x) {
        coords[i] = is64 ? raw[2 * i] : raw[i];
    }
}

// One block per 32x32 output tile. Phase 1: ordered compaction of intersecting
// patches. Phase 2: per patch, threads cooperatively STREAM the overlap window
// in patch-memory order (aligned float4; lanes = 8 quads x 8 rows, 2 channels
// per wave) and accumulate into an LDS tile via ds_add_f32 (atomicAdd on LDS,
// non-returning -> fire-and-forget, no dependent lgkmcnt chains). R8's plain
// `+=` was correct but the compiler couldn't disprove aliasing and serialized
// every RMW (ds_read..ds_write..wait ~240cy x 32 x 12 patches) -> 1.6 TB/s.
// Addresses stay clamped to the patch row (R8 fix): mask with UNCLAMPED px.
// Phase 3: fused normalize + coalesced store.
__global__ __launch_bounds__(256, 4)
void gather_kernel(const float* __restrict__ logits,
                   const int* __restrict__ coords,
                   float* __restrict__ out) {
    const int b   = blockIdx.z;
    const int ty0 = blockIdx.y * TH;
    const int tx0 = blockIdx.x * TW;
    const int tid = threadIdx.x;

    __shared__ float s_acc[C_ * TH * LPAD];   // 8448 floats = 33.0 KiB
    __shared__ float s_cnt[TH * LPAD];        // 1056 floats =  4.1 KiB
    __shared__ int   s_rc[K_];                // packed (r<<16)|c, compacted
    __shared__ int   s_kk[K_];                // accepted patch index
    __shared__ unsigned long long s_mask[4];

    // --- Phase 0: zero accumulators (pre-sync, overlaps compaction) ---
    for (int i = tid; i < C_ * TH * LPAD; i += 256) s_acc[i] = 0.0f;
    for (int i = tid; i < TH * LPAD; i += 256) s_cnt[i] = 0.0f;

    // --- Phase 1: ordered accept-list compaction (one coord per thread) ---
    int2 cc = ((const int2*)coords)[b * K_ + tid];
    bool hit = (cc.x < ty0 + TH) && (cc.x + PS > ty0) &&
               (cc.y < tx0 + TW) && (cc.y + PS > tx0);
    {
        unsigned long long m = __ballot(hit);
        const int wid = tid >> 6, lane = tid & 63;
        if (lane == 0) s_mask[wid] = m;
        __syncthreads();
        int base = 0;
        for (int w = 0; w < wid; ++w) base += __popcll(s_mask[w]);
        if (hit) {
            int pos = base + __popcll(m & ((1ull << lane) - 1ull));
            s_rc[pos] = (cc.x << 16) | cc.y;
            s_kk[pos] = tid;
        }
    }
    int nacc = 0;
    for (int w = 0; w < 4; ++w) nacc += __popcll(s_mask[w]);
    __syncthreads();

    // --- Phase 2: patch-order streaming accumulate (ds_add_f32) ---
    const int wv   = tid >> 6;    // wave 0..3 -> owns channels wv, wv+4
    const int lane = tid & 63;
    const int rr   = lane >> 3;   // row within group of 8
    const int qq   = lane & 7;    // float4 column index

    for (int t = 0; t < nacc; ++t) {
        const int rcp = __builtin_amdgcn_readfirstlane(s_rc[t]);
        const int kk  = __builtin_amdgcn_readfirstlane(s_kk[t]);
        const int r = rcp >> 16, c = rcp & 0xffff;
        const float* __restrict__ pbase =
            logits + (((size_t)(b * K_ + kk)) << 15);  // * C*ps*ps

        const int pxlo = max(0, tx0 - c);
        const int pxhi = min(PS - 1, tx0 + TW - 1 - c);
        const int pylo = max(0, ty0 - r);
        const int pyhi = min(PS - 1, ty0 + TH - 1 - r);
        const int c4lo = pxlo & ~3;          // 16B-aligned window start
        const int h    = pyhi - pylo + 1;
        const int ng   = (h + 7) >> 3;       // row groups of 8 (<=4)

        const int py   = pylo + rr;               // this lane's row in group 0
        const int px4u = c4lo + (qq << 2);        // unclamped quad col (mask)
        const int px4  = min(px4u, PS - 4);       // clamped quad col (address)

        float4 v0[4], v1[4];
        int pyc[4]; bool rok[4];
#pragma unroll
        for (int g = 0; g < 4; ++g) {
            const int p = py + g * 8;
            rok[g] = (g < ng) && (p <= pyhi);
            pyc[g] = min(p, pyhi);
        }
        const float* ch0 = pbase + ((size_t)wv << 12);
        const float* ch1 = pbase + ((size_t)(wv + 4) << 12);
        // Issue ALL window loads first (independent cluster; no consumer yet).
#pragma unroll
        for (int g = 0; g < 4; ++g) {
            if (g < ng) v0[g] = *(const float4*)(ch0 + (pyc[g] << 6) + px4);
        }
#pragma unroll
        for (int g = 0; g < 4; ++g) {
            if (g < ng) v1[g] = *(const float4*)(ch1 + (pyc[g] << 6) + px4);
        }

        // LDS accumulate: single-instruction ds_add_f32, no dependent chains.
#pragma unroll
        for (int g = 0; g < 4; ++g) {
            if (g >= ng) continue;
            const int ly = r + pyc[g] - ty0;            // in [0,TH)
            float* a0 = &s_acc[wv * TH * LPAD + ly * LPAD];        // ch wv
            float* a1 = &s_acc[(wv + 4) * TH * LPAD + ly * LPAD];  // ch wv+4
            float* cn = &s_cnt[ly * LPAD];
            const float c0[4] = {v0[g].x, v0[g].y, v0[g].z, v0[g].w};
            const float c1[4] = {v1[g].x, v1[g].y, v1[g].z, v1[g].w};
#pragma unroll
            for (int comp = 0; comp < 4; ++comp) {
                const int px = px4u + comp;             // UNCLAMPED for mask
                const bool ok = rok[g] && (px >= pxlo) && (px <= pxhi);
                if (ok) {
                    const int lx = c + px - tx0;        // in [0,TW)
                    atomicAdd(&a0[lx], c0[comp]);
                    atomicAdd(&a1[lx], c1[comp]);
                    if (wv == 0) atomicAdd(&cn[lx], 1.0f);
                }
            }
        }

        // Rare 9th quad (window spans 9 aligned quads): cols c4lo+32..pxhi.
        // Executes only when c4lo+32 <= pxhi <= 63 -> px4b <= 60 (in-row).
        if (c4lo + 32 <= pxhi) {
            const int px4b = c4lo + 32;
            float4 e0[4], e1[4];
#pragma unroll
            for (int g = 0; g < 4; ++g) {
                if (g < ng) e0[g] = *(const float4*)(ch0 + (pyc[g] << 6) + px4b);
            }
#pragma unroll
            for (int g = 0; g < 4; ++g) {
                if (g < ng) e1[g] = *(const float4*)(ch1 + (pyc[g] << 6) + px4b);
            }
#pragma unroll
            for (int g = 0; g < 4; ++g) {
                if (g >= ng) continue;
                const int ly = r + pyc[g] - ty0;
                float* a0 = &s_acc[wv * TH * LPAD + ly * LPAD];
                float* a1 = &s_acc[(wv + 4) * TH * LPAD + ly * LPAD];
                float* cn = &s_cnt[ly * LPAD];
                const float c0[4] = {e0[g].x, e0[g].y, e0[g].z, e0[g].w};
                const float c1[4] = {e1[g].x, e1[g].y, e1[g].z, e1[g].w};
#pragma unroll
                for (int comp = 0; comp < 4; ++comp) {
                    const int px = px4b + comp;
                    const bool ok = rok[g] && (qq == 0) && (px <= pxhi);
                    if (ok) {
                        const int lx = c + px - tx0;
                        atomicAdd(&a0[lx], c0[comp]);
                        atomicAdd(&a1[lx], c1[comp]);
                        if (wv == 0) atomicAdd(&cn[lx], 1.0f);
                    }
                }
            }
        }
    }
    __syncthreads();

    // --- Phase 3: fused normalize + coalesced store ---
    const int lx  = tid & 31;
    const int ly0 = tid >> 5;   // rows ly0 + {0,8,16,24}
#pragma unroll
    for (int j = 0; j < 4; ++j) {
        const int ly = ly0 + j * 8;
        const int y  = ty0 + ly;
        const int x  = tx0 + lx;
        const float cv = s_cnt[ly * LPAD + lx];
        const bool covered = cv > 1e-6f;
        const float inv = 1.0f / fmaxf(cv, 1e-6f);
#pragma unroll
        for (int ch = 0; ch < C_; ++ch) {
            const float a = s_acc[ch * TH * LPAD + ly * LPAD + lx];
            const float vo = covered ? a * inv : -10.0f;
            out[(((size_t)(b * C_ + ch)) << 18) + y * W_ + x] = vo;
        }
    }
}

extern "C" void kernel_launch(void* const* d_in, const int* in_sizes, int n_in,
                              void* d_out, int out_size, void* d_ws, size_t ws_size,
                              hipStream_t stream) {
    const float* logits = (const float*)d_in[0];
    const int* raw_coords = (const int*)d_in[1];
    float* out = (float*)d_out;

    int* coords = (int*)d_ws;  // 16 KiB decoded coords

    decode_coords_kernel<<<1, 256, 0, stream>>>(raw_coords, coords, B_ * K_ * 2);

    dim3 grid(W_ / TW, H_ / TH, B_);  // 16 x 16 x 8 = 2048 blocks
    gather_kernel<<<grid, 256, 0, stream>>>(logits, coords, out);
}

// Round 10
// 100.613 us; speedup vs baseline: 5.9534x; 5.9534x over previous
//
#include <hip/hip_runtime.h>

#define B_   8
#define K_   256
#define C_   8
#define PS   64
#define H_   512
#define W_   512
#define TH   32
#define TW   32

// Detect whether coords buffer is int64 (little-endian lo/hi pairs, hi==0 since
// coords are small non-negative) or already int32; write decoded int32 coords.
__global__ void decode_coords_kernel(const int* __restrict__ raw,
                                     int* __restrict__ coords, int n) {
    __shared__ int s_nonzero;
    if (threadIdx.x == 0) s_nonzero = 0;
    __syncthreads();
    int local = 0;
    for (int i = 2 * threadIdx.x + 1; i < n; i += 2 * blockDim.x) {
        if (raw[i] != 0) local = 1;
    }
    if (local) atomicOr(&s_nonzero, 1);
    __syncthreads();
    bool is64 = (s_nonzero == 0);  // all odd words zero -> int64 layout
    for (int i = threadIdx.x; i < n; i += blockDim.x) {
        coords[i] = is64 ? raw[2 * i] : raw[i];
    }
}

// One block per (32x32 tile, CHANNEL-PAIR): grid 16x16x(B*4)=8192 blocks.
// Register-accumulate gather (R4 structure — best so far at 104us), but each
// block handles only 2 channels: per-thread per-patch work is 8 clamped loads
// + 8 FMAs (vs 32), and 4x more blocks give 32 blocks/CU for occupancy
// smoothing and memory-level parallelism (R4 measured 28% occupancy with
// exactly 8 blocks/CU and 32-deep dependent clusters). cnt is recomputed
// locally from validity flags (no extra traffic). Addresses are clamped into
// the overlap window (always in-bounds; masked by UNCLAMPED coords).
__global__ __launch_bounds__(256)
void gather_kernel(const float* __restrict__ logits,
                   const int* __restrict__ coords,
                   float* __restrict__ out) {
    const int b   = blockIdx.z >> 2;
    const int cp  = blockIdx.z & 3;    // channel pair: {2cp, 2cp+1}
    const int ty0 = blockIdx.y * TH;
    const int tx0 = blockIdx.x * TW;
    const int tid = threadIdx.x;

    __shared__ int s_rc[K_];    // packed (r<<16)|c, compacted in k-order
    __shared__ int s_kk[K_];    // accepted patch index
    __shared__ unsigned long long s_mask[4];

    // --- Phase 1: ordered accept-list compaction (one coord per thread) ---
    {
        int2 cc = ((const int2*)coords)[b * K_ + tid];
        bool hit = (cc.x < ty0 + TH) && (cc.x + PS > ty0) &&
                   (cc.y < tx0 + TW) && (cc.y + PS > tx0);
        unsigned long long m = __ballot(hit);
        const int wid = tid >> 6, lane = tid & 63;
        if (lane == 0) s_mask[wid] = m;
        __syncthreads();
        int base = 0;
        for (int w = 0; w < wid; ++w) base += __popcll(s_mask[w]);
        if (hit) {
            int pos = base + __popcll(m & ((1ull << lane) - 1ull));
            s_rc[pos] = (cc.x << 16) | cc.y;
            s_kk[pos] = tid;
        }
    }
    int nacc = 0;
    for (int w = 0; w < 4; ++w) nacc += __popcll(s_mask[w]);
    __syncthreads();

    // --- Phase 2: register-accumulate gather, 2 channels ---
    float acc0[4], acc1[4], cnt[4];
#pragma unroll
    for (int j = 0; j < 4; ++j) { acc0[j] = acc1[j] = cnt[j] = 0.0f; }

    const int x  = tx0 + (tid & 31);   // owned column
    const int y0 = ty0 + (tid >> 5);   // owned rows: y0 + {0,8,16,24}

#pragma unroll 2
    for (int t = 0; t < nacc; ++t) {
        const int rcp = __builtin_amdgcn_readfirstlane(s_rc[t]);
        const int kk  = __builtin_amdgcn_readfirstlane(s_kk[t]);
        const int r = rcp >> 16, c = rcp & 0xffff;
        const float* __restrict__ pbase =
            logits + (((size_t)(b * K_ + kk)) << 15) + ((size_t)(2 * cp) << 12);

        // Valid overlap window in patch coords (non-empty by construction).
        const int pxlo = max(0, tx0 - c);
        const int pxhi = min(PS - 1, tx0 + TW - 1 - c);
        const int pylo = max(0, ty0 - r);
        const int pyhi = min(PS - 1, ty0 + TH - 1 - r);

        const int  px  = x - c;
        const int  pxc = min(max(px, pxlo), pxhi);   // in-window (in-bounds)
        const bool okx = (px == pxc);

        float f[4];
        int   off[4];
#pragma unroll
        for (int j = 0; j < 4; ++j) {
            const int py  = y0 + j * 8 - r;
            const int pyc = min(max(py, pylo), pyhi);
            f[j]   = (okx && (py == pyc)) ? 1.0f : 0.0f;
            off[j] = (pyc << 6) + pxc;               // inside window, fetched anyway
        }

        float v0[4], v1[4];
#pragma unroll
        for (int j = 0; j < 4; ++j) v0[j] = pbase[off[j]];
#pragma unroll
        for (int j = 0; j < 4; ++j) v1[j] = pbase[4096 + off[j]];

#pragma unroll
        for (int j = 0; j < 4; ++j) {
            cnt[j] += f[j];
            acc0[j] = fmaf(v0[j], f[j], acc0[j]);
            acc1[j] = fmaf(v1[j], f[j], acc1[j]);
        }
    }

    // --- Phase 3: fused finalize + store (2 channels, written exactly once) ---
#pragma unroll
    for (int j = 0; j < 4; ++j) {
        const int y = y0 + j * 8;
        const bool covered = cnt[j] > 1e-6f;
        const float inv = 1.0f / fmaxf(cnt[j], 1e-6f);
        const size_t o0 = (((size_t)(b * C_ + 2 * cp)) << 18) + y * W_ + x;
        out[o0]                 = covered ? acc0[j] * inv : -10.0f;
        out[o0 + (1ull << 18)]  = covered ? acc1[j] * inv : -10.0f;
    }
}

extern "C" void kernel_launch(void* const* d_in, const int* in_sizes, int n_in,
                              void* d_out, int out_size, void* d_ws, size_t ws_size,
                              hipStream_t stream) {
    const float* logits = (const float*)d_in[0];
    const int* raw_coords = (const int*)d_in[1];
    float* out = (float*)d_out;

    int* coords = (int*)d_ws;  // 16 KiB decoded coords

    decode_coords_kernel<<<1, 256, 0, stream>>>(raw_coords, coords, B_ * K_ * 2);

    dim3 grid(W_ / TW, H_ / TH, B_ * 4);  // 16 x 16 x 32 = 8192 blocks
    gather_kernel<<<grid, 256, 0, stream>>>(logits, coords, out);
}